// Round 3
// baseline (175.711 us; speedup 1.0000x reference)
//
#include <hip/hip_runtime.h>
#include <hip/hip_bf16.h>

// Sparse gather-FFN, LDS/VALU co-bound.
// R3 change: packed f32 math. Each packed-bf16 word (2 rows) is unpacked to
// a float2 and consumed by ONE v_pk_fma_f32 (LLVM selects V_PK_FMA_F32 from
// <2 x float> fma on gfx950). Inner loop per feature: 8 unpack + 4 pk_fma
// = 12 VALU inst vs 16 scalar previously (~20% VALU cut; VALU was 87% busy).

#define NB   32768
#define NIN  128
#define NL   8
#define NW   256
#define NK   16
#define RPB  8                        // batch rows per block (8 bf16 = 16 B)
#define STORED (NIN + (NL - 1) * NW)  // 1920 features ever re-read

typedef float v2f __attribute__((ext_vector_type(2)));

__device__ __forceinline__ unsigned bf16pair(float a, float b) {
    // RNE f32->bf16, packed (a in low 16, b in high 16)
    unsigned ua = __float_as_uint(a);
    unsigned ub = __float_as_uint(b);
    ua = (ua + 0x7fffu + ((ua >> 16) & 1u)) >> 16;
    ub = (ub + 0x7fffu + ((ub >> 16) & 1u)) >> 16;
    return ua | (ub << 16);
}

// one packed word -> float2 {low-row, high-row}, exact
__device__ __forceinline__ v2f unpack2(unsigned u) {
    v2f v;
    v[0] = __uint_as_float(u << 16);
    v[1] = __uint_as_float(u & 0xffff0000u);
    return v;
}

__device__ __forceinline__ void fma_feat(v2f acc[4], float w, uint4 p) {
    v2f w2; w2[0] = w; w2[1] = w;
    acc[0] = __builtin_elementwise_fma(unpack2(p.x), w2, acc[0]);
    acc[1] = __builtin_elementwise_fma(unpack2(p.y), w2, acc[1]);
    acc[2] = __builtin_elementwise_fma(unpack2(p.z), w2, acc[2]);
    acc[3] = __builtin_elementwise_fma(unpack2(p.w), w2, acc[3]);
}

__global__ __launch_bounds__(256, 4)
void ffn_gather_kernel(const float* __restrict__ inputs,
                       const float* __restrict__ weights,
                       const float* __restrict__ biases,
                       const int*   __restrict__ edge_idx,
                       float* __restrict__ out)
{
    __shared__ uint4 vals[STORED];   // vals[f] = 8 bf16 rows of feature f

    const int t = threadIdx.x;                       // 0..255, unit id
    const long long row0 = (long long)blockIdx.x * RPB;

    // ---- stage the 128 input features for 8 rows (feature-major, bf16) ----
    if (t < NIN) {
        float v[RPB];
        #pragma unroll
        for (int r = 0; r < RPB; ++r) v[r] = inputs[(row0 + r) * NIN + t];
        uint4 p;
        p.x = bf16pair(v[0], v[1]);
        p.y = bf16pair(v[2], v[3]);
        p.z = bf16pair(v[4], v[5]);
        p.w = bf16pair(v[6], v[7]);
        vals[t] = p;
    }
    __syncthreads();

    // ---- layers ----
    #pragma unroll
    for (int l = 0; l < NL; ++l) {
        const int base = (l * NW + t) * NK;
        const int4*   iq = (const int4*)(edge_idx + base);
        const float4* wq = (const float4*)(weights + base);

        const float b = biases[l * NW + t];
        v2f acc[4];
        #pragma unroll
        for (int j = 0; j < 4; ++j) { acc[j][0] = b; acc[j][1] = b; }

        #pragma unroll
        for (int kk = 0; kk < NK / 4; ++kk) {
            const int4   i4 = iq[kk];
            const float4 w4 = wq[kk];
            const uint4 p0 = vals[i4.x];
            const uint4 p1 = vals[i4.y];
            const uint4 p2 = vals[i4.z];
            const uint4 p3 = vals[i4.w];
            fma_feat(acc, w4.x, p0);
            fma_feat(acc, w4.y, p1);
            fma_feat(acc, w4.z, p2);
            fma_feat(acc, w4.w, p3);
        }

        float s[RPB];
        #pragma unroll
        for (int j = 0; j < 4; ++j) {
            s[2 * j + 0] = 1.0f / (1.0f + __expf(-acc[j][0]));
            s[2 * j + 1] = 1.0f / (1.0f + __expf(-acc[j][1]));
        }

        if (l < NL - 1) {
            // layer-l writes land above every layer-l read region -> no
            // pre-write sync needed; one barrier before next layer's reads.
            uint4 p;
            p.x = bf16pair(s[0], s[1]);
            p.y = bf16pair(s[2], s[3]);
            p.z = bf16pair(s[4], s[5]);
            p.w = bf16pair(s[6], s[7]);
            vals[NIN + l * NW + t] = p;
        } else {
            // final layer: fp32 straight to out, no bf16 roundtrip
            #pragma unroll
            for (int r = 0; r < RPB; ++r)
                out[(row0 + r) * NW + t] = s[r];
        }
        __syncthreads();
    }
}

extern "C" void kernel_launch(void* const* d_in, const int* in_sizes, int n_in,
                              void* d_out, int out_size, void* d_ws, size_t ws_size,
                              hipStream_t stream)
{
    const float* inputs   = (const float*)d_in[0];
    const float* weights  = (const float*)d_in[1];
    const float* biases   = (const float*)d_in[2];
    const int*   edge_idx = (const int*)d_in[3];
    float* out = (float*)d_out;

    dim3 grid(NB / RPB);   // 4096
    dim3 block(NW);        // 256
    ffn_gather_kernel<<<grid, block, 0, stream>>>(inputs, weights, biases,
                                                  edge_idx, out);
}

// Round 5
// 143.803 us; speedup vs baseline: 1.2219x; 1.2219x over previous
//
#include <hip/hip_runtime.h>
#include <hip/hip_bf16.h>
#include <hip/hip_fp16.h>

// Sparse gather-FFN, LDS/VALU co-bound.
// R5: same as R4 (packed-f16 activations consumed via v_fma_mix_f32,
// 8 inst/feature, 8 independent acc chains) with the compile fix:
// __builtin_amdgcn_cvt_pkrtz returns a __fp16 ext-vector -> bit_cast it.

#define NB   32768
#define NIN  128
#define NL   8
#define NW   256
#define NK   16
#define RPB  8                        // batch rows per block (8 f16 = 16 B)
#define STORED (NIN + (NL - 1) * NW)  // 1920 features ever re-read

typedef _Float16 h2 __attribute__((ext_vector_type(2)));
typedef __fp16   fp16v2 __attribute__((ext_vector_type(2)));

__device__ __forceinline__ unsigned pk16(float a, float b) {
    fp16v2 p = __builtin_amdgcn_cvt_pkrtz(a, b);   // v_cvt_pkrtz_f16_f32
    return __builtin_bit_cast(unsigned, p);
}

// 8 row-MACs from one 16B packed-f16 word; forms 8x v_fma_mix_f32
__device__ __forceinline__ void fma_feat(float acc[RPB], float w, uint4 p) {
    const h2 h0 = __builtin_bit_cast(h2, p.x);
    const h2 h1 = __builtin_bit_cast(h2, p.y);
    const h2 h2v = __builtin_bit_cast(h2, p.z);
    const h2 h3 = __builtin_bit_cast(h2, p.w);
    acc[0] = fmaf((float)h0[0], w, acc[0]);
    acc[1] = fmaf((float)h0[1], w, acc[1]);
    acc[2] = fmaf((float)h1[0], w, acc[2]);
    acc[3] = fmaf((float)h1[1], w, acc[3]);
    acc[4] = fmaf((float)h2v[0], w, acc[4]);
    acc[5] = fmaf((float)h2v[1], w, acc[5]);
    acc[6] = fmaf((float)h3[0], w, acc[6]);
    acc[7] = fmaf((float)h3[1], w, acc[7]);
}

__global__ __launch_bounds__(256, 5)
void ffn_gather_kernel(const float* __restrict__ inputs,
                       const float* __restrict__ weights,
                       const float* __restrict__ biases,
                       const int*   __restrict__ edge_idx,
                       float* __restrict__ out)
{
    __shared__ uint4 vals[STORED];   // vals[f] = 8 f16 rows of feature f

    const int t = threadIdx.x;                       // 0..255, unit id
    const long long row0 = (long long)blockIdx.x * RPB;

    // ---- stage the 128 input features for 8 rows (feature-major, f16) ----
    if (t < NIN) {
        float v[RPB];
        #pragma unroll
        for (int r = 0; r < RPB; ++r) v[r] = inputs[(row0 + r) * NIN + t];
        uint4 p;
        p.x = pk16(v[0], v[1]);
        p.y = pk16(v[2], v[3]);
        p.z = pk16(v[4], v[5]);
        p.w = pk16(v[6], v[7]);
        vals[t] = p;
    }
    __syncthreads();

    // ---- layers ----
    #pragma unroll
    for (int l = 0; l < NL; ++l) {
        const int base = (l * NW + t) * NK;
        const int4*   iq = (const int4*)(edge_idx + base);
        const float4* wq = (const float4*)(weights + base);

        const float b = biases[l * NW + t];
        float acc[RPB];
        #pragma unroll
        for (int r = 0; r < RPB; ++r) acc[r] = b;

        #pragma unroll
        for (int kk = 0; kk < NK / 4; ++kk) {
            const int4   i4 = iq[kk];
            const float4 w4 = wq[kk];
            const uint4 p0 = vals[i4.x];
            const uint4 p1 = vals[i4.y];
            const uint4 p2 = vals[i4.z];
            const uint4 p3 = vals[i4.w];
            fma_feat(acc, w4.x, p0);
            fma_feat(acc, w4.y, p1);
            fma_feat(acc, w4.z, p2);
            fma_feat(acc, w4.w, p3);
        }

        float s[RPB];
        #pragma unroll
        for (int r = 0; r < RPB; ++r)
            s[r] = 1.0f / (1.0f + __expf(-acc[r]));

        if (l < NL - 1) {
            // layer-l writes land above every layer-l read region -> no
            // pre-write sync needed; one barrier before next layer's reads.
            uint4 p;
            p.x = pk16(s[0], s[1]);
            p.y = pk16(s[2], s[3]);
            p.z = pk16(s[4], s[5]);
            p.w = pk16(s[6], s[7]);
            vals[NIN + l * NW + t] = p;
            __syncthreads();
        } else {
            // final layer: fp32 straight to out, no f16 roundtrip
            #pragma unroll
            for (int r = 0; r < RPB; ++r)
                out[(row0 + r) * NW + t] = s[r];
        }
    }
}

extern "C" void kernel_launch(void* const* d_in, const int* in_sizes, int n_in,
                              void* d_out, int out_size, void* d_ws, size_t ws_size,
                              hipStream_t stream)
{
    const float* inputs   = (const float*)d_in[0];
    const float* weights  = (const float*)d_in[1];
    const float* biases   = (const float*)d_in[2];
    const int*   edge_idx = (const int*)d_in[3];
    float* out = (float*)d_out;

    dim3 grid(NB / RPB);   // 4096
    dim3 block(NW);        // 256
    ffn_gather_kernel<<<grid, block, 0, stream>>>(inputs, weights, biases,
                                                  edge_idx, out);
}

// Round 6
// 139.162 us; speedup vs baseline: 1.2626x; 1.0334x over previous
//
#include <hip/hip_runtime.h>
#include <hip/hip_bf16.h>
#include <hip/hip_fp16.h>

// Sparse gather-FFN. Pipes per CU (R5 measured): DS ~68us (41 base + 27
// conflict), VALU ~62us, dur 89us.
// R6: packed-f16 FMA. Slot layout already pairs rows per dword ->
// v_pk_fma_f16 does 2 row-MACs/inst (full rate, unlike pk_fma_f32 which
// regressed in R3): 4 inst/feature vs 8. Accumulation in f16 (pre-acts ~+-4;
// predicted absmax ~0.01 < 0.0196 threshold; fallback = f32 acc).
// Pre-pass kernel packs edge_idx*16 (byte offsets) and (w,w) f16 pairs into
// d_ws -> kills per-read lshl + per-feature cvt in the hot loop.

#define NB   32768
#define NIN  128
#define NL   8
#define NW   256
#define NK   16
#define RPB  8                        // batch rows per block (8 f16 = 16 B)
#define STORED (NIN + (NL - 1) * NW)  // 1920 features ever re-read
#define NPARAM (NL * NW * NK)         // 32768 (l,u,k) entries

typedef __fp16 fp16v2 __attribute__((ext_vector_type(2)));

__device__ __forceinline__ unsigned pk16(float a, float b) {
    fp16v2 p = __builtin_amdgcn_cvt_pkrtz(a, b);   // v_cvt_pkrtz_f16_f32
    return __builtin_bit_cast(unsigned, p);
}

__device__ __forceinline__ __half2 as_h2(unsigned u) {
    return __builtin_bit_cast(__half2, u);
}

// 8 row-MACs from one 16B packed-f16 word: 4x v_pk_fma_f16
__device__ __forceinline__ void fma_feat(__half2 acc[4], __half2 w2, uint4 p) {
    acc[0] = __hfma2(as_h2(p.x), w2, acc[0]);
    acc[1] = __hfma2(as_h2(p.y), w2, acc[1]);
    acc[2] = __hfma2(as_h2(p.z), w2, acc[2]);
    acc[3] = __hfma2(as_h2(p.w), w2, acc[3]);
}

template <bool PRE>
__global__ __launch_bounds__(256, 5)
void ffn_gather_kernel(const float* __restrict__ inputs,
                       const float* __restrict__ weights,
                       const float* __restrict__ biases,
                       const int*   __restrict__ edge_idx,
                       const int*   __restrict__ idxb,   // pre-scaled byte offs
                       const unsigned* __restrict__ wpk, // packed (w,w) f16
                       float* __restrict__ out)
{
    __shared__ uint4 vals[STORED];   // vals[f] = 8 f16 rows of feature f

    const int t = threadIdx.x;                       // 0..255, unit id
    const long long row0 = (long long)blockIdx.x * RPB;
    const char* vbase = (const char*)vals;

    // ---- stage the 128 input features for 8 rows (feature-major, f16) ----
    if (t < NIN) {
        float v[RPB];
        #pragma unroll
        for (int r = 0; r < RPB; ++r) v[r] = inputs[(row0 + r) * NIN + t];
        uint4 p;
        p.x = pk16(v[0], v[1]);
        p.y = pk16(v[2], v[3]);
        p.z = pk16(v[4], v[5]);
        p.w = pk16(v[6], v[7]);
        vals[t] = p;
    }
    __syncthreads();

    // ---- layers ----
    #pragma unroll
    for (int l = 0; l < NL; ++l) {
        const int base = (l * NW + t) * NK;

        const float b = biases[l * NW + t];
        __half2 acc[4];
        const __half2 bb = __float2half2_rn(b);
        #pragma unroll
        for (int j = 0; j < 4; ++j) acc[j] = bb;

        #pragma unroll
        for (int kk = 0; kk < NK / 4; ++kk) {
            int4 o4;          // byte offsets into vals
            __half2 w0, w1, w2, w3;
            if (PRE) {
                o4 = ((const int4*)(idxb + base))[kk];
                uint4 wp = ((const uint4*)(wpk + base))[kk];
                w0 = as_h2(wp.x); w1 = as_h2(wp.y);
                w2 = as_h2(wp.z); w3 = as_h2(wp.w);
            } else {
                int4 i4 = ((const int4*)(edge_idx + base))[kk];
                o4.x = i4.x << 4; o4.y = i4.y << 4;
                o4.z = i4.z << 4; o4.w = i4.w << 4;
                float4 w4 = ((const float4*)(weights + base))[kk];
                w0 = __float2half2_rn(w4.x);
                w1 = __float2half2_rn(w4.y);
                w2 = __float2half2_rn(w4.z);
                w3 = __float2half2_rn(w4.w);
            }
            const uint4 p0 = *(const uint4*)(vbase + o4.x);
            const uint4 p1 = *(const uint4*)(vbase + o4.y);
            const uint4 p2 = *(const uint4*)(vbase + o4.z);
            const uint4 p3 = *(const uint4*)(vbase + o4.w);
            fma_feat(acc, w0, p0);
            fma_feat(acc, w1, p1);
            fma_feat(acc, w2, p2);
            fma_feat(acc, w3, p3);
        }

        float s[RPB];
        #pragma unroll
        for (int j = 0; j < 4; ++j) {
            s[2 * j + 0] = 1.0f / (1.0f + __expf(-__low2float(acc[j])));
            s[2 * j + 1] = 1.0f / (1.0f + __expf(-__high2float(acc[j])));
        }

        if (l < NL - 1) {
            // layer-l writes land above every layer-l read region -> no
            // pre-write sync needed; one barrier before next layer's reads.
            uint4 p;
            p.x = pk16(s[0], s[1]);
            p.y = pk16(s[2], s[3]);
            p.z = pk16(s[4], s[5]);
            p.w = pk16(s[6], s[7]);
            vals[NIN + l * NW + t] = p;
            __syncthreads();
        } else {
            // final layer: fp32 straight to out
            #pragma unroll
            for (int r = 0; r < RPB; ++r)
                out[(row0 + r) * NW + t] = s[r];
        }
    }
}

// pre-pass: byte-offset indices + packed (w,w) f16 weights into ws
__global__ __launch_bounds__(256)
void prepass_kernel(const float* __restrict__ weights,
                    const int* __restrict__ edge_idx,
                    int* __restrict__ idxb,
                    unsigned* __restrict__ wpk)
{
    const int i = blockIdx.x * 256 + threadIdx.x;   // 0..32767
    idxb[i] = edge_idx[i] << 4;
    const float w = weights[i];
    wpk[i] = pk16(w, w);
}

extern "C" void kernel_launch(void* const* d_in, const int* in_sizes, int n_in,
                              void* d_out, int out_size, void* d_ws, size_t ws_size,
                              hipStream_t stream)
{
    const float* inputs   = (const float*)d_in[0];
    const float* weights  = (const float*)d_in[1];
    const float* biases   = (const float*)d_in[2];
    const int*   edge_idx = (const int*)d_in[3];
    float* out = (float*)d_out;

    dim3 grid(NB / RPB);   // 4096
    dim3 block(NW);        // 256

    const size_t need = (size_t)NPARAM * 4 * 2;     // 256 KB
    if (ws_size >= need) {
        int*      idxb = (int*)d_ws;
        unsigned* wpk  = (unsigned*)((char*)d_ws + (size_t)NPARAM * 4);
        prepass_kernel<<<NPARAM / 256, 256, 0, stream>>>(weights, edge_idx,
                                                         idxb, wpk);
        ffn_gather_kernel<true><<<grid, block, 0, stream>>>(
            inputs, weights, biases, edge_idx, idxb, wpk, out);
    } else {
        ffn_gather_kernel<false><<<grid, block, 0, stream>>>(
            inputs, weights, biases, edge_idx, nullptr, nullptr, out);
    }
}